// Round 1
// 95.741 us; speedup vs baseline: 1.1225x; 1.1225x over previous
//
#include <hip/hip_runtime.h>
#include <hip/hip_bf16.h>
#include <stdint.h>

// Problem constants (fixed shapes from reference: B=4096, D=256, N=2B)
#define NROWS 8192
#define DDIM  256
#define BM    128
#define BN    128
#define BK    64
#define KSTEPS (DDIM / BK)              // 4 K-steps
#define NTILE (NROWS / BM)              // 64 tile-rows
#define NTRI  (NTILE * (NTILE + 1) / 2) // 2080 upper-tri tiles
// TAU = 0.1 -> z = cos/TAU; exp(z-10) = exp2(cos*L2E/TAU - 10*L2E)
// L2E/TAU == 10*L2E == 14.4269504: e = exp2(SCEXP*(cos - 1)), one FMA + one exp.
#define SCEXP 14.4269504088896340736f

// LDS: double-buffered staging A0|B0|A1|B1, 16 KB each = 64 KB.
// Epilogue scratch aliases buffer region after the K-loop:
//   colAP: float2 [128 cols][5 slots]  = 5120 B
//   rowAP: float2 [128 rows][18 slots] = 18432 B
#define COL_STRIDE2 5
#define ROW_STRIDE2 18
#define ROWAP_OFF   5120
#define SMEM_BYTES  65536

typedef __attribute__((ext_vector_type(8))) short short8;
typedef __attribute__((ext_vector_type(4))) float f32x4;

typedef const __attribute__((address_space(1))) uint32_t glb_u32;
typedef __attribute__((address_space(3))) uint32_t lds_u32;

__device__ __forceinline__ void load_lds16(const unsigned short* g, unsigned short* l) {
  // 16B per lane, LDS dest = wave-uniform base + lane*16 (HW scatter)
  __builtin_amdgcn_global_load_lds((glb_u32*)g, (lds_u32*)l, 16, 0, 0);
}

__device__ __forceinline__ unsigned short f2bf(float x) {
  __hip_bfloat16 h = __float2bfloat16(x);
  return *reinterpret_cast<unsigned short*>(&h);
}

// Kernel 1: bf16 concat(f) PRE-NORMALIZED (inv-norm folded into operands so
// the GEMM accumulator is the cosine directly), labels, zero S arrays + out.
__global__ void __launch_bounds__(256)
milnce_prep(const float* __restrict__ feat, const float* __restrict__ pos,
            const int* __restrict__ labels, unsigned short* __restrict__ fb,
            int* __restrict__ lab, float* __restrict__ S_all,
            float* __restrict__ S_pos, float* __restrict__ out) {
  const int wave = threadIdx.x >> 6;
  const int lane = threadIdx.x & 63;
  const int row  = blockIdx.x * 4 + wave;   // 2048 blocks -> 8192 rows

  const float* src = (row < 4096) ? (feat + (size_t)row * DDIM)
                                  : (pos + (size_t)(row - 4096) * DDIM);
  float4 v = ((const float4*)src)[lane];    // 4 contiguous fp32 per lane

  float ss = v.x*v.x + v.y*v.y + v.z*v.z + v.w*v.w;
  #pragma unroll
  for (int m = 1; m < 64; m <<= 1) ss += __shfl_xor(ss, m, 64);  // all lanes get sum
  const float inv = 1.0f / sqrtf(ss);

  ushort4 o;
  o.x = f2bf(v.x * inv); o.y = f2bf(v.y * inv);
  o.z = f2bf(v.z * inv); o.w = f2bf(v.w * inv);
  ((ushort4*)(fb + (size_t)row * DDIM))[lane] = o;

  const int tid = blockIdx.x * 256 + threadIdx.x;
  if (tid < NROWS) {
    lab[tid]   = labels[tid & 4095];  // concat duplicates labels
    S_all[tid] = 0.0f;
    S_pos[tid] = 0.0f;
  }
  if (tid == 0) out[0] = 0.0f;
}

// Kernel 2: fused f@f^T (bf16 MFMA) + exp2 masked sums over UPPER-TRI tiles.
// Round-5 change: the old 8-step K-loop drained vmcnt(0) at every
// __syncthreads (latency-bound: MfmaUtil 14%, VALUBusy 31%, occ 16%).
// Now: BK=64 (4 K-steps), double-buffered staging, counted s_waitcnt vmcnt(8)
// + raw s_barrier so next tile's 8 global_load_lds stay in flight across the
// 32-MFMA compute phase (T3/T4 recipe). setprio(1) around the MFMA cluster.
__global__ void __launch_bounds__(256, 2)
milnce_gemm(const unsigned short* __restrict__ fb, const int* __restrict__ lab,
            float* __restrict__ S_all, float* __restrict__ S_pos) {
  __shared__ __align__(16) char smem[SMEM_BYTES];

  // Closed-form diagonal decode: tile t on diagonal d (bj-bi=d), cum(d)=d*(129-d)/2.
  int t = blockIdx.x;
  int d = (int)((129.0f - sqrtf(16641.0f - 8.0f * (float)t)) * 0.5f);
  while (d * (129 - d) / 2 > t) --d;                 // fp fixups (<=1 iter)
  while ((d + 1) * (128 - d) / 2 <= t) ++d;
  const int rem = t - d * (129 - d) / 2;
  const int bi = rem, bj = rem + d;

  const int tid  = threadIdx.x;
  const int wave = tid >> 6;
  const int lane = tid & 63;
  const int quad = lane >> 4;
  const int l15  = lane & 15;
  const int wm   = wave >> 1;   // 2x2 wave grid over 128x128
  const int wn   = wave & 1;
  const int rowBase = bi * BM;
  const int colBase = bj * BN;

  f32x4 acc[4][4];
  #pragma unroll
  for (int i = 0; i < 4; ++i)
    #pragma unroll
    for (int j = 0; j < 4; ++j) acc[i][j] = (f32x4){0.f, 0.f, 0.f, 0.f};

  // Staging: 1024 slots of 16B per tile (128 rows x 8 k-octets). Slot
  // s = i*256 + wave*64 + lane; row = s>>3; global octet g = (s&7)^(row&7)
  // (XOR swizzle pre-applied on the GLOBAL source; LDS dest stays linear).
  const unsigned short* gA[4];
  const unsigned short* gB[4];
  #pragma unroll
  for (int i = 0; i < 4; ++i) {
    const int s = i * 256 + wave * 64 + lane;
    const int r = s >> 3;
    const int g = (s & 7) ^ (r & 7);
    gA[i] = fb + (size_t)(rowBase + r) * DDIM + g * 8;
    gB[i] = fb + (size_t)(colBase + r) * DDIM + g * 8;
  }
  unsigned short* lds = (unsigned short*)smem;
  const int dstW = wave * 512;            // (wave*64 slots)*8 elem

  // Prologue: stage kt=0 into buffer 0 (A @0, B @8192 elem).
  #pragma unroll
  for (int i = 0; i < 4; ++i) load_lds16(gA[i], lds + dstW + i * 2048);
  #pragma unroll
  for (int i = 0; i < 4; ++i) load_lds16(gB[i], lds + 8192 + dstW + i * 2048);

  // Reader: global octet q of row r lives at slot q^(r&7); r&7 == l15&7.
  const int jx   = (quad ^ (l15 & 7)) * 8;     // elem offset, kk=0; kk=1 -> ^32
  const int rowA = (wm * 64 + l15) * BK;
  const int rowB = (wn * 64 + l15) * BK;

  #pragma unroll
  for (int kt = 0; kt < KSTEPS; ++kt) {
    const int cur = kt & 1;
    if (kt + 1 < KSTEPS) {
      const int nxtOff = (cur ^ 1) * 16384;    // elem offset of next A|B pair
      const int ko = (kt + 1) * BK;
      #pragma unroll
      for (int i = 0; i < 4; ++i)
        load_lds16(gA[i] + ko, lds + nxtOff + dstW + i * 2048);
      #pragma unroll
      for (int i = 0; i < 4; ++i)
        load_lds16(gB[i] + ko, lds + nxtOff + 8192 + dstW + i * 2048);
      // wait only for the PREVIOUS step's 8 loads; the 8 just issued stay in flight
      asm volatile("s_waitcnt vmcnt(8)" ::: "memory");
    } else {
      asm volatile("s_waitcnt vmcnt(0)" ::: "memory");
    }
    __builtin_amdgcn_s_barrier();              // everyone's buf[cur] is ready

    const unsigned short* As = lds + cur * 16384;
    const unsigned short* Bs = As + 8192;
    #pragma unroll
    for (int kk = 0; kk < 2; ++kk) {
      short8 a[4], b[4];
      const int jo = jx ^ (kk * 32);
      #pragma unroll
      for (int mi = 0; mi < 4; ++mi)
        a[mi] = *(const short8*)&As[rowA + mi * 1024 + jo];
      #pragma unroll
      for (int ni = 0; ni < 4; ++ni)
        b[ni] = *(const short8*)&Bs[rowB + ni * 1024 + jo];
      __builtin_amdgcn_s_setprio(1);
      #pragma unroll
      for (int mi = 0; mi < 4; ++mi)
        #pragma unroll
        for (int ni = 0; ni < 4; ++ni)
          acc[mi][ni] = __builtin_amdgcn_mfma_f32_16x16x32_bf16(a[mi], b[ni], acc[mi][ni], 0, 0, 0);
      __builtin_amdgcn_s_setprio(0);
    }
    // all this wave's ds_reads delivered before signaling; barrier protects
    // buf[cur] from next iteration's overwrite
    asm volatile("s_waitcnt lgkmcnt(0)" ::: "memory");
    __builtin_amdgcn_s_barrier();
  }

  // Epilogue. C/D layout (16x16x32): col = lane&15, row = quad*4 + reg.
  // acc is the cosine directly (operands pre-normalized):
  //   e = exp2(SCEXP*acc - SCEXP) == exp(z - 10), shift cancels in the loss.
  float2* colAP = (float2*)smem;                    // staging dead -> alias
  float2* rowAP = (float2*)(smem + ROWAP_OFF);

  int cl[4], colg[4];
  #pragma unroll
  for (int ni = 0; ni < 4; ++ni) {
    colg[ni] = colBase + wn * 64 + ni * 16 + l15;
    cl[ni]   = lab[colg[ni]];
  }

  const bool offdiag = (bi != bj);
  float2 capk[4] = {{0.f,0.f},{0.f,0.f},{0.f,0.f},{0.f,0.f}};

  if (offdiag) {
    #pragma unroll
    for (int mi = 0; mi < 4; ++mi) {
      const int rbase = wm * 64 + mi * 16 + quad * 4;
      const int4 rl4 = *(const int4*)&lab[rowBase + rbase];
      #pragma unroll
      for (int r = 0; r < 4; ++r) {
        const int rl = (r == 0) ? rl4.x : (r == 1) ? rl4.y : (r == 2) ? rl4.z : rl4.w;
        float sx = 0.f, sy = 0.f;
        #pragma unroll
        for (int ni = 0; ni < 4; ++ni) {
          float e  = exp2f(__builtin_fmaf(acc[mi][ni][r], SCEXP, -SCEXP));
          float ep = (rl == cl[ni]) ? e : 0.f;   // no diagonal here (bi != bj)
          capk[ni].x += e; capk[ni].y += ep;
          sx += e; sy += ep;
        }
        rowAP[(rbase + r) * ROW_STRIDE2 + wn * 16 + l15] = make_float2(sx, sy);
      }
    }
  } else {
    #pragma unroll
    for (int mi = 0; mi < 4; ++mi) {
      const int rbase = wm * 64 + mi * 16 + quad * 4;
      const int4 rl4 = *(const int4*)&lab[rowBase + rbase];
      #pragma unroll
      for (int r = 0; r < 4; ++r) {
        const int rl = (r == 0) ? rl4.x : (r == 1) ? rl4.y : (r == 2) ? rl4.z : rl4.w;
        const int rowg = rowBase + rbase + r;
        #pragma unroll
        for (int ni = 0; ni < 4; ++ni) {
          float e = exp2f(__builtin_fmaf(acc[mi][ni][r], SCEXP, -SCEXP));
          if (rowg == colg[ni]) e = 0.f;         // mask diagonal entries
          float ep = (rl == cl[ni]) ? e : 0.f;
          capk[ni].x += e; capk[ni].y += ep;
        }
      }
    }
  }

  // Column partials -> LDS (4 quad slots per column), conflict-free stride.
  #pragma unroll
  for (int ni = 0; ni < 4; ++ni)
    colAP[(wn * 64 + ni * 16 + l15) * COL_STRIDE2 + quad] = capk[ni];

  __syncthreads();

  if (tid < 128) {
    // Column commit: sum 4 quad partials, one coalesced 64-lane atomic each.
    const float2* cp = &colAP[tid * COL_STRIDE2];
    float2 c0 = cp[0], c1 = cp[1], c2 = cp[2], c3 = cp[3];
    atomicAdd(&S_all[colBase + tid], (c0.x + c1.x) + (c2.x + c3.x));
    atomicAdd(&S_pos[colBase + tid], (c0.y + c1.y) + (c2.y + c3.y));
  } else if (offdiag) {
    // Row commit (== skipped transposed tile's columns): sum 16 lane partials.
    const int rr = tid - 128;
    const float2* rp = &rowAP[rr * ROW_STRIDE2];
    float sx = 0.f, sy = 0.f;
    #pragma unroll
    for (int i = 0; i < 16; ++i) { sx += rp[i].x; sy += rp[i].y; }
    atomicAdd(&S_all[rowBase + rr], sx);
    atomicAdd(&S_pos[rowBase + rr], sy);
  }
}

// Kernel 3: loss = sum_i log(S_all[i]) - log(S_pos[i])  (the +10 shifts cancel).
// Widened 1 block -> 32 blocks (one element per thread) + one atomic per block;
// out is zeroed by prep.
__global__ void __launch_bounds__(256)
milnce_final(const float* __restrict__ S_all, const float* __restrict__ S_pos,
             float* __restrict__ out) {
  const int i = blockIdx.x * 256 + threadIdx.x;   // 32*256 == NROWS
  float s = logf(S_all[i]) - logf(S_pos[i]);
  #pragma unroll
  for (int m = 1; m < 64; m <<= 1) s += __shfl_xor(s, m, 64);
  __shared__ float red[4];
  if ((threadIdx.x & 63) == 0) red[threadIdx.x >> 6] = s;
  __syncthreads();
  if (threadIdx.x == 0) atomicAdd(out, (red[0] + red[1]) + (red[2] + red[3]));
}

extern "C" void kernel_launch(void* const* d_in, const int* in_sizes, int n_in,
                              void* d_out, int out_size, void* d_ws, size_t ws_size,
                              hipStream_t stream) {
  const float* feat   = (const float*)d_in[0];
  const float* pos    = (const float*)d_in[1];
  const int*   labels = (const int*)d_in[2];

  char* ws = (char*)d_ws;
  unsigned short* fb    = (unsigned short*)ws;                       // 4 MB bf16 normalized concat
  int*            lab   = (int*)  (ws + 4u * 1024 * 1024);           // 32 KB
  float*          S_all = (float*)(ws + 4u * 1024 * 1024 + 32 * 1024);
  float*          S_pos = (float*)(ws + 4u * 1024 * 1024 + 64 * 1024);
  float*          out   = (float*)d_out;

  hipLaunchKernelGGL(milnce_prep, dim3(NROWS / 4), dim3(256), 0, stream,
                     feat, pos, labels, fb, lab, S_all, S_pos, out);
  hipLaunchKernelGGL(milnce_gemm, dim3(NTRI), dim3(256), 0, stream,
                     fb, lab, S_all, S_pos);
  hipLaunchKernelGGL(milnce_final, dim3(32), dim3(256), 0, stream,
                     S_all, S_pos, out);
}